// Round 9
// baseline (428.945 us; speedup 1.0000x reference)
//
#include <hip/hip_runtime.h>

// ---------------------------------------------------------------------------
// ScaleDotProductAttention: q=Q@Wq^T+bq; k=K@Wk^T+bk; v=V@Wv^T+bv
// S = q@k^T/32 (mask==1 -> -inf), P=softmax(S), out = P@v
// B=8, L1=L2=2048, D=E=1024. bf16 MFMA 16x16x32, fp32 accum.
// Round 9: fused fp32->bf16 A-staging in the projections, now with a 2-tile
// register pipeline (load A(t+2) while writing A(t+1); 4-phase lead > HBM
// latency — round 7 failed with 1-phase lead). All 3 projections in ONE
// z=3 dispatch; weight converts in one dispatch. qk/pv/softmax unchanged.
// ---------------------------------------------------------------------------

using u16 = unsigned short;
using frag_ab = __attribute__((ext_vector_type(8))) short;   // 8 bf16 (4 VGPRs)
using frag_cd = __attribute__((ext_vector_type(4))) float;   // 4 fp32

#define BAR() asm volatile("s_barrier" ::: "memory")
#define WAITV(n) asm volatile("s_waitcnt vmcnt(" #n ")" ::: "memory")
#define WAITLGKM0() do { asm volatile("s_waitcnt lgkmcnt(0)" ::: "memory"); \
                         __builtin_amdgcn_sched_barrier(0); } while (0)
#define L(d, ab, h) (lds + (((d) * 4) + ((ab) * 2) + (h)) * 8192)

__device__ __forceinline__ u16 f2bf(float f) {
  union { float f; unsigned u; } c; c.f = f;
  unsigned u = c.u;
  return (u16)((u + 0x7FFFu + ((u >> 16) & 1u)) >> 16);   // RNE
}
__device__ __forceinline__ u16 f2h(float f) {
  union { _Float16 h; u16 u; } c; c.h = (_Float16)f; return c.u;
}
__device__ __forceinline__ float h2f(u16 u) {
  union { u16 u; _Float16 h; } c; c.u = u; return (float)c.h;
}
__device__ __forceinline__ frag_ab pack8(float4 x, float4 y) {
  frag_ab p;
  p[0] = (short)f2bf(x.x); p[1] = (short)f2bf(x.y);
  p[2] = (short)f2bf(x.z); p[3] = (short)f2bf(x.w);
  p[4] = (short)f2bf(y.x); p[5] = (short)f2bf(y.y);
  p[6] = (short)f2bf(y.z); p[7] = (short)f2bf(y.w);
  return p;
}

__device__ __forceinline__ void async_ld16(const void* g, void* l) {
  __builtin_amdgcn_global_load_lds(
      (const __attribute__((address_space(1))) unsigned*)g,
      (__attribute__((address_space(3))) unsigned*)l, 16, 0, 0);
}

// 3 weight matrices fp32->bf16 in one dispatch (z selects)
__global__ void cvtw3(const float* __restrict__ a, const float* __restrict__ b,
                      const float* __restrict__ c, u16* __restrict__ out) {
  const float* in = blockIdx.z == 0 ? a : (blockIdx.z == 1 ? b : c);
  u16* o = out + (long)blockIdx.z * 1048576L;
  long i = ((long)blockIdx.x * 256 + threadIdx.x) * 4;
  float4 v = *reinterpret_cast<const float4*>(in + i);
  *reinterpret_cast<ushort4*>(o + i) =
      make_ushort4(f2bf(v.x), f2bf(v.y), f2bf(v.z), f2bf(v.w));
}

// Stage one 128x64 bf16 half-tile via global_load_lds (linear dest,
// 3-bit XOR swizzle pre-applied to the GLOBAL source 16B-slot).
__device__ __forceinline__ void stage_half(const u16* __restrict__ g_rowbase,
                                           long Kstr, u16* l_half,
                                           int wave, int lane) {
  const int t = wave * 64 + lane;
  #pragma unroll
  for (int i = 0; i < 2; i++) {
    const int row = i * 64 + (t >> 3);
    const int cb  = (t & 7) * 16;
    const int cbs = cb ^ ((row & 7) << 4);
    async_ld16(g_rowbase + (long)row * Kstr + (cbs >> 1),
               l_half + i * 4096 + wave * 512);
  }
}

// swizzled fragment read/write of 8 bf16 on a [128][64] half
__device__ __forceinline__ frag_ab ld_frag(const u16* half_base, int r, int k) {
  const int idx = r * 64 + (k ^ ((r & 7) << 3));
  return *reinterpret_cast<const frag_ab*>(half_base + idx);
}
__device__ __forceinline__ void st_frag(u16* half_base, int r, int s, frag_ab v) {
  *reinterpret_cast<frag_ab*>(half_base + r * 64 + ((s ^ (r & 7)) << 3)) = v;
}

// ===== generic bf16 GEMM body (qk / pv), unchanged round-6 schedule =====
// OUT_MODE: 0 fp32 C[M][N]; 3 fp16 C[M][N].
template<int OUT_MODE>
__device__ __forceinline__ void
gemm256_body(const u16* __restrict__ A, const u16* __restrict__ Bt,
             void* __restrict__ Cout, int M, int N, int K,
             long sA, long sB, long sC, float scale, u16* lds)
{
  const int gx = gridDim.x, gy = gridDim.y, gz = gridDim.z;
  const int nwg = gx * gy * gz;
  const int lin = ((int)blockIdx.z * gy + blockIdx.y) * gx + blockIdx.x;
  const int q8 = nwg >> 3, r8 = nwg & 7;
  const int xcd = lin & 7, idx8 = lin >> 3;
  const int swz = (xcd < r8 ? xcd * (q8 + 1) : r8 * (q8 + 1) + (xcd - r8) * q8) + idx8;
  const int z = swz / (gx * gy);
  const int rem = swz % (gx * gy);
  const int m0 = (rem / gx) * 256;
  const int n0 = (rem % gx) * 256;

  const u16* Ab = A + (long)z * sA;
  const u16* Bb = Bt + (long)z * sB;

  const int tid = threadIdx.x;
  const int wave = tid >> 6, lane = tid & 63;
  const int wm = wave >> 2, wn = wave & 3;
  const int ln15 = lane & 15, kof = (lane >> 4) * 8;
  const int rB0 = (wn & 1) * 64;
  const int NT = K >> 6;

  frag_cd acc[8][4];
  #pragma unroll
  for (int i = 0; i < 8; i++)
    #pragma unroll
    for (int j = 0; j < 4; j++)
      acc[i][j] = (frag_cd){0.f, 0.f, 0.f, 0.f};

  stage_half(Ab + (long)(m0 +   0) * K, K, L(0, 0, 0), wave, lane);
  stage_half(Ab + (long)(m0 + 128) * K, K, L(0, 0, 1), wave, lane);
  stage_half(Bb + (long)(n0 +   0) * K, K, L(0, 1, 0), wave, lane);
  stage_half(Bb + (long)(n0 + 128) * K, K, L(0, 1, 1), wave, lane);
  {
    const int t1 = (1 < NT) ? 1 : 0;
    stage_half(Bb + (long)(n0 +   0) * K + t1 * 64, K, L(1, 1, 0), wave, lane);
    stage_half(Bb + (long)(n0 + 128) * K + t1 * 64, K, L(1, 1, 1), wave, lane);
  }
  WAITV(4);
  BAR();

  for (int t = 0; t < NT; ++t) {
    const int d = t & 1;
    const u16* Al = L(d, 0, wm);
    const u16* Bl = L(d, 1, wn >> 1);
    const int tA = (t + 1 < NT) ? t + 1 : NT - 1;
    const int tB = (t + 2 < NT) ? t + 2 : NT - 1;

    frag_ab bf[4][2], af[2][2];

    // q0
    #pragma unroll
    for (int bn = 0; bn < 4; ++bn)
      #pragma unroll
      for (int kk = 0; kk < 2; ++kk)
        bf[bn][kk] = ld_frag(Bl, rB0 + bn * 16 + ln15, kk * 32 + kof);
    #pragma unroll
    for (int am = 0; am < 2; ++am)
      #pragma unroll
      for (int kk = 0; kk < 2; ++kk)
        af[am][kk] = ld_frag(Al, am * 16 + ln15, kk * 32 + kof);
    stage_half(Ab + (long)(m0 +   0) * K + tA * 64, K, L(d ^ 1, 0, 0), wave, lane);
    stage_half(Ab + (long)(m0 + 128) * K + tA * 64, K, L(d ^ 1, 0, 1), wave, lane);
    BAR();
    __builtin_amdgcn_s_setprio(1);
    #pragma unroll
    for (int am = 0; am < 2; ++am)
      #pragma unroll
      for (int bn = 0; bn < 4; ++bn)
        #pragma unroll
        for (int kk = 0; kk < 2; ++kk)
          acc[am][bn] = __builtin_amdgcn_mfma_f32_16x16x32_bf16(af[am][kk], bf[bn][kk], acc[am][bn], 0, 0, 0);
    __builtin_amdgcn_s_setprio(0);
    BAR();

    // q1
    #pragma unroll
    for (int am = 0; am < 2; ++am)
      #pragma unroll
      for (int kk = 0; kk < 2; ++kk)
        af[am][kk] = ld_frag(Al, (2 + am) * 16 + ln15, kk * 32 + kof);
    stage_half(Bb + (long)(n0 + 0) * K + tB * 64, K, L(d, 1, 0), wave, lane);
    BAR();
    __builtin_amdgcn_s_setprio(1);
    #pragma unroll
    for (int am = 0; am < 2; ++am)
      #pragma unroll
      for (int bn = 0; bn < 4; ++bn)
        #pragma unroll
        for (int kk = 0; kk < 2; ++kk)
          acc[2 + am][bn] = __builtin_amdgcn_mfma_f32_16x16x32_bf16(af[am][kk], bf[bn][kk], acc[2 + am][bn], 0, 0, 0);
    __builtin_amdgcn_s_setprio(0);
    BAR();

    // q2
    #pragma unroll
    for (int am = 0; am < 2; ++am)
      #pragma unroll
      for (int kk = 0; kk < 2; ++kk)
        af[am][kk] = ld_frag(Al, (4 + am) * 16 + ln15, kk * 32 + kof);
    stage_half(Bb + (long)(n0 + 128) * K + tB * 64, K, L(d, 1, 1), wave, lane);
    BAR();
    __builtin_amdgcn_s_setprio(1);
    #pragma unroll
    for (int am = 0; am < 2; ++am)
      #pragma unroll
      for (int bn = 0; bn < 4; ++bn)
        #pragma unroll
        for (int kk = 0; kk < 2; ++kk)
          acc[4 + am][bn] = __builtin_amdgcn_mfma_f32_16x16x32_bf16(af[am][kk], bf[bn][kk], acc[4 + am][bn], 0, 0, 0);
    __builtin_amdgcn_s_setprio(0);
    BAR();

    // q3
    #pragma unroll
    for (int am = 0; am < 2; ++am)
      #pragma unroll
      for (int kk = 0; kk < 2; ++kk)
        af[am][kk] = ld_frag(Al, (6 + am) * 16 + ln15, kk * 32 + kof);
    BAR();
    __builtin_amdgcn_s_setprio(1);
    #pragma unroll
    for (int am = 0; am < 2; ++am)
      #pragma unroll
      for (int bn = 0; bn < 4; ++bn)
        #pragma unroll
        for (int kk = 0; kk < 2; ++kk)
          acc[6 + am][bn] = __builtin_amdgcn_mfma_f32_16x16x32_bf16(af[am][kk], bf[bn][kk], acc[6 + am][bn], 0, 0, 0);
    __builtin_amdgcn_s_setprio(0);
    WAITV(4);
    BAR();
  }

  WAITV(0);
  BAR();

  const int cl = lane & 15;
  const int rb = (lane >> 4) * 4;
  #pragma unroll
  for (int bn = 0; bn < 4; ++bn) {
    const int gcol = n0 + wn * 64 + bn * 16 + cl;
    #pragma unroll
    for (int am = 0; am < 8; ++am) {
      #pragma unroll
      for (int r = 0; r < 4; ++r) {
        const int grow = m0 + wm * 128 + am * 16 + rb + r;
        const float val = acc[am][bn][r] * scale;
        if (OUT_MODE == 0) {
          ((float*)Cout)[(long)z * sC + (long)grow * N + gcol] = val;
        } else {
          ((u16*)Cout)[(long)z * sC + (long)grow * N + gcol] = f2h(val);
        }
      }
    }
  }
}

__global__ void __launch_bounds__(512, 2)
qk_gemm(const u16* A, const u16* Bt, void* C,
        int M, int N, int K, long sA, long sB, long sC, float scale) {
  __shared__ u16 lds[8 * 8192];
  gemm256_body<3>(A, Bt, C, M, N, K, sA, sB, sC, scale, lds);
}
__global__ void __launch_bounds__(512, 2)
pv_gemm(const u16* A, const u16* Bt, void* C,
        int M, int N, int K, long sA, long sB, long sC, float scale) {
  __shared__ u16 lds[8 * 8192];
  gemm256_body<0>(A, Bt, C, M, N, K, sA, sB, sC, scale, lds);
}

// ===== fused projections: A fp32 (Q/K/V selected by z), convert in-staging =====
// Grid (4, 64, 3). M=16384, N=K=1024, NT=16 (even). 2-tile register pipeline:
// tile t WRITES A(t+1) (regs loaded at t-1) and ISSUES loads for A(t+2).
// Per-tile VMEM issues: q0 4 reg-loads, q1 4 reg-loads + 2 gld(B), q2 2 gld(B)
// = 12 -> WAITV(12) at q3 drains everything older (incl. B(t+1)).

#define FTILE(T, W, Ld) do {                                                   \
    const int t = (T);                                                         \
    const int d = t & 1;                                                       \
    const u16* Al = L(d, 0, wm);                                               \
    const u16* Bl = L(d, 1, wn >> 1);                                          \
    const int tB = (t + 2 < 16) ? t + 2 : 15;                                  \
    frag_ab bf[4][2], af[2][2];                                                \
    /* q0: 12 ds_reads; write A(t+1) h0; issue loads A(t+2) h0 */              \
    _Pragma("unroll")                                                          \
    for (int bn = 0; bn < 4; ++bn)                                             \
      _Pragma("unroll")                                                        \
      for (int kk = 0; kk < 2; ++kk)                                           \
        bf[bn][kk] = ld_frag(Bl, rB0 + bn * 16 + ln15, kk * 32 + kof);         \
    _Pragma("unroll")                                                          \
    for (int am = 0; am < 2; ++am)                                             \
      _Pragma("unroll")                                                        \
      for (int kk = 0; kk < 2; ++kk)                                           \
        af[am][kk] = ld_frag(Al, am * 16 + ln15, kk * 32 + kof);               \
    st_frag(L(d ^ 1, 0, 0), sr,      ss, pack8(W[0], W[1]));                   \
    st_frag(L(d ^ 1, 0, 0), sr + 64, ss, pack8(W[2], W[3]));                   \
    { const float* ap = Abf + (long)(m0 + sr) * 1024 + tB * 64 + ss * 8;       \
      Ld[0] = *(const float4*)(ap);                                            \
      Ld[1] = *(const float4*)(ap + 4);                                        \
      Ld[2] = *(const float4*)(ap + 64L * 1024);                               \
      Ld[3] = *(const float4*)(ap + 64L * 1024 + 4); }                         \
    BAR();                                                                     \
    __builtin_amdgcn_s_setprio(1);                                             \
    _Pragma("unroll")                                                          \
    for (int am = 0; am < 2; ++am)                                             \
      _Pragma("unroll")                                                        \
      for (int bn = 0; bn < 4; ++bn)                                           \
        _Pragma("unroll")                                                      \
        for (int kk = 0; kk < 2; ++kk)                                         \
          acc[am][bn] = __builtin_amdgcn_mfma_f32_16x16x32_bf16(af[am][kk], bf[bn][kk], acc[am][bn], 0, 0, 0); \
    __builtin_amdgcn_s_setprio(0);                                             \
    BAR();                                                                     \
    /* q1: af23; write A(t+1) h1; issue loads A(t+2) h1; stage Bh0(t+2) */     \
    _Pragma("unroll")                                                          \
    for (int am = 0; am < 2; ++am)                                             \
      _Pragma("unroll")                                                        \
      for (int kk = 0; kk < 2; ++kk)                                           \
        af[am][kk] = ld_frag(Al, (2 + am) * 16 + ln15, kk * 32 + kof);         \
    st_frag(L(d ^ 1, 0, 1), sr,      ss, pack8(W[4], W[5]));                   \
    st_frag(L(d ^ 1, 0, 1), sr + 64, ss, pack8(W[6], W[7]));                   \
    { const float* ap = Abf + (long)(m0 + 128 + sr) * 1024 + tB * 64 + ss * 8; \
      Ld[4] = *(const float4*)(ap);                                            \
      Ld[5] = *(const float4*)(ap + 4);                                        \
      Ld[6] = *(const float4*)(ap + 64L * 1024);                               \
      Ld[7] = *(const float4*)(ap + 64L * 1024 + 4); }                         \
    stage_half(Wbz + (long)(n0 + 0) * 1024 + tB * 64, 1024, L(d, 1, 0), wave, lane); \
    BAR();                                                                     \
    __builtin_amdgcn_s_setprio(1);                                             \
    _Pragma("unroll")                                                          \
    for (int am = 0; am < 2; ++am)                                             \
      _Pragma("unroll")                                                        \
      for (int bn = 0; bn < 4; ++bn)                                           \
        _Pragma("unroll")                                                      \
        for (int kk = 0; kk < 2; ++kk)                                         \
          acc[2 + am][bn] = __builtin_amdgcn_mfma_f32_16x16x32_bf16(af[am][kk], bf[bn][kk], acc[2 + am][bn], 0, 0, 0); \
    __builtin_amdgcn_s_setprio(0);                                             \
    BAR();                                                                     \
    /* q2: af45; stage Bh1(t+2); commit A-writes */                            \
    _Pragma("unroll")                                                          \
    for (int am = 0; am < 2; ++am)                                             \
      _Pragma("unroll")                                                        \
      for (int kk = 0; kk < 2; ++kk)                                           \
        af[am][kk] = ld_frag(Al, (4 + am) * 16 + ln15, kk * 32 + kof);         \
    stage_half(Wbz + (long)(n0 + 128) * 1024 + tB * 64, 1024, L(d, 1, 1), wave, lane); \
    WAITLGKM0();                                                               \
    BAR();                                                                     \
    __builtin_amdgcn_s_setprio(1);                                             \
    _Pragma("unroll")                                                          \
    for (int am = 0; am < 2; ++am)                                             \
      _Pragma("unroll")                                                        \
      for (int bn = 0; bn < 4; ++bn)                                           \
        _Pragma("unroll")                                                      \
        for (int kk = 0; kk < 2; ++kk)                                         \
          acc[4 + am][bn] = __builtin_amdgcn_mfma_f32_16x16x32_bf16(af[am][kk], bf[bn][kk], acc[4 + am][bn], 0, 0, 0); \
    __builtin_amdgcn_s_setprio(0);                                             \
    BAR();                                                                     \
    /* q3: af67; mfma; counted wait keeps tile-t's 12 issues in flight */      \
    _Pragma("unroll")                                                          \
    for (int am = 0; am < 2; ++am)                                             \
      _Pragma("unroll")                                                        \
      for (int kk = 0; kk < 2; ++kk)                                           \
        af[am][kk] = ld_frag(Al, (6 + am) * 16 + ln15, kk * 32 + kof);         \
    BAR();                                                                     \
    __builtin_amdgcn_s_setprio(1);                                             \
    _Pragma("unroll")                                                          \
    for (int am = 0; am < 2; ++am)                                             \
      _Pragma("unroll")                                                        \
      for (int bn = 0; bn < 4; ++bn)                                           \
        _Pragma("unroll")                                                      \
        for (int kk = 0; kk < 2; ++kk)                                         \
          acc[6 + am][bn] = __builtin_amdgcn_mfma_f32_16x16x32_bf16(af[am][kk], bf[bn][kk], acc[6 + am][bn], 0, 0, 0); \
    __builtin_amdgcn_s_setprio(0);                                             \
    WAITV(12);                                                                 \
    BAR();                                                                     \
  } while (0)

__global__ void __launch_bounds__(512, 1)
proj3_gemm(const float* __restrict__ Qf, const float* __restrict__ Kf,
           const float* __restrict__ Vf, const u16* __restrict__ Wb,
           const float* __restrict__ bq, const float* __restrict__ bk,
           const float* __restrict__ bv, u16* __restrict__ qkb,
           u16* __restrict__ vT)
{
  __shared__ u16 lds[8 * 8192];

  const int gx = gridDim.x, gy = gridDim.y;   // 4, 64 (z=3)
  const int nwg = gx * gy * gridDim.z;
  const int lin = ((int)blockIdx.z * gy + blockIdx.y) * gx + blockIdx.x;
  const int q8 = nwg >> 3, r8 = nwg & 7;
  const int xcd = lin & 7, idx8 = lin >> 3;
  const int swz = (xcd < r8 ? xcd * (q8 + 1) : r8 * (q8 + 1) + (xcd - r8) * q8) + idx8;
  const int z = swz / (gx * gy);
  const int rem = swz % (gx * gy);
  const int m0 = (rem / gx) * 256;
  const int n0 = (rem % gx) * 256;

  const float* Abf = z == 0 ? Qf : (z == 1 ? Kf : Vf);
  const u16* Wbz = Wb + (long)z * 1048576L;
  const float* bias = z == 0 ? bq : (z == 1 ? bk : bv);

  const int tid = threadIdx.x;
  const int wave = tid >> 6, lane = tid & 63;
  const int wm = wave >> 2, wn = wave & 3;
  const int ln15 = lane & 15, kof = (lane >> 4) * 8;
  const int rB0 = (wn & 1) * 64;
  const int sr = tid >> 3;   // staging row 0..63
  const int ss = tid & 7;    // staging 16B slot

  frag_cd acc[8][4];
  #pragma unroll
  for (int i = 0; i < 8; i++)
    #pragma unroll
    for (int j = 0; j < 4; j++)
      acc[i][j] = (frag_cd){0.f, 0.f, 0.f, 0.f};

  float4 RA[8], RB[8];

  // ---- prologue: A(0)->RA (8), B(0) gld (4), B(1) gld (4), A(1)->RB (8) ----
  {
    const float* a0 = Abf + (long)(m0 + sr) * 1024 + ss * 8;
    RA[0] = *(const float4*)(a0);
    RA[1] = *(const float4*)(a0 + 4);
    RA[2] = *(const float4*)(a0 +  64L * 1024);
    RA[3] = *(const float4*)(a0 +  64L * 1024 + 4);
    RA[4] = *(const float4*)(a0 + 128L * 1024);
    RA[5] = *(const float4*)(a0 + 128L * 1024 + 4);
    RA[6] = *(const float4*)(a0 + 192L * 1024);
    RA[7] = *(const float4*)(a0 + 192L * 1024 + 4);
  }
  stage_half(Wbz + (long)(n0 +   0) * 1024, 1024, L(0, 1, 0), wave, lane);
  stage_half(Wbz + (long)(n0 + 128) * 1024, 1024, L(0, 1, 1), wave, lane);
  stage_half(Wbz + (long)(n0 +   0) * 1024 + 64, 1024, L(1, 1, 0), wave, lane);
  stage_half(Wbz + (long)(n0 + 128) * 1024 + 64, 1024, L(1, 1, 1), wave, lane);
  {
    const float* a1 = Abf + (long)(m0 + sr) * 1024 + 64 + ss * 8;
    RB[0] = *(const float4*)(a1);
    RB[1] = *(const float4*)(a1 + 4);
    RB[2] = *(const float4*)(a1 +  64L * 1024);
    RB[3] = *(const float4*)(a1 +  64L * 1024 + 4);
    RB[4] = *(const float4*)(a1 + 128L * 1024);
    RB[5] = *(const float4*)(a1 + 128L * 1024 + 4);
    RB[6] = *(const float4*)(a1 + 192L * 1024);
    RB[7] = *(const float4*)(a1 + 192L * 1024 + 4);
  }
  WAITV(16);   // RA (A(0)) landed
  st_frag(L(0, 0, 0), sr,      ss, pack8(RA[0], RA[1]));
  st_frag(L(0, 0, 0), sr + 64, ss, pack8(RA[2], RA[3]));
  st_frag(L(0, 0, 1), sr,      ss, pack8(RA[4], RA[5]));
  st_frag(L(0, 0, 1), sr + 64, ss, pack8(RA[6], RA[7]));
  WAITV(12);   // B(0) landed (leaves B(1)+RB in flight)
  WAITLGKM0();
  BAR();

  // ---- main loop: NT=16, unrolled by 2 for static register-set roles ----
  for (int t2 = 0; t2 < 16; t2 += 2) {
    FTILE(t2,     RB, RA);   // write A(t2+1) from RB, load A(t2+2) -> RA
    FTILE(t2 + 1, RA, RB);   // write A(t2+2) from RA, load A(t2+3) -> RB
  }

  WAITV(0);
  BAR();

  // ---- epilogue ----
  const int cl = lane & 15;
  const int rb = (lane >> 4) * 4;
  #pragma unroll
  for (int bn = 0; bn < 4; ++bn) {
    const int gcol = n0 + wn * 64 + bn * 16 + cl;
    const float badd = bias[gcol];
    #pragma unroll
    for (int am = 0; am < 8; ++am) {
      #pragma unroll
      for (int r = 0; r < 4; ++r) {
        const int grow = m0 + wm * 128 + am * 16 + rb + r;
        const float val = acc[am][bn][r] + badd;
        if (z < 2) {
          qkb[(long)z * 16777216L + (long)grow * 1024 + gcol] = f2bf(val);
        } else {
          vT[((long)(grow >> 11) * 1024 + gcol) * 2048L + (grow & 2047)] = f2bf(val);
        }
      }
    }
  }
}

// softmax over fp16 S slab: blockIdx.x = row; mask batch = row>>11
__global__ void softmax_rows_h(const u16* __restrict__ S, const int* __restrict__ Km,
                               u16* __restrict__ P)
{
  const long row = blockIdx.x;
  const int b = (int)(row >> 11);
  const u16* s = S + row * 2048;
  const int* mask = Km + (long)b * 2048;
  u16* p = P + row * 2048;

  const int t = threadIdx.x;
  const int base = t * 8;

  ushort4 r0 = *reinterpret_cast<const ushort4*>(s + base);
  ushort4 r1 = *reinterpret_cast<const ushort4*>(s + base + 4);
  int4 mA = *reinterpret_cast<const int4*>(mask + base);
  int4 mB = *reinterpret_cast<const int4*>(mask + base + 4);

  float vals[8] = {h2f(r0.x), h2f(r0.y), h2f(r0.z), h2f(r0.w),
                   h2f(r1.x), h2f(r1.y), h2f(r1.z), h2f(r1.w)};
  const int mk[8] = {mA.x, mA.y, mA.z, mA.w, mB.x, mB.y, mB.z, mB.w};

  float mx = -3.0e38f;
  #pragma unroll
  for (int i = 0; i < 8; i++) if (!mk[i]) mx = fmaxf(mx, vals[i]);
  #pragma unroll
  for (int off = 32; off > 0; off >>= 1) mx = fmaxf(mx, __shfl_xor(mx, off));

  __shared__ float redm[4], reds[4];
  const int wave = t >> 6, lane = t & 63;
  if (lane == 0) redm[wave] = mx;
  __syncthreads();
  mx = fmaxf(fmaxf(redm[0], redm[1]), fmaxf(redm[2], redm[3]));

  float e[8]; float sum = 0.f;
  #pragma unroll
  for (int i = 0; i < 8; i++) { e[i] = mk[i] ? 0.f : __expf(vals[i] - mx); sum += e[i]; }
  #pragma unroll
  for (int off = 32; off > 0; off >>= 1) sum += __shfl_xor(sum, off);
  if (lane == 0) reds[wave] = sum;
  __syncthreads();
  sum = reds[0] + reds[1] + reds[2] + reds[3];
  const float inv = 1.f / sum;

  *reinterpret_cast<ushort4*>(p + base) =
      make_ushort4(f2bf(e[0]*inv), f2bf(e[1]*inv), f2bf(e[2]*inv), f2bf(e[3]*inv));
  *reinterpret_cast<ushort4*>(p + base + 4) =
      make_ushort4(f2bf(e[4]*inv), f2bf(e[5]*inv), f2bf(e[6]*inv), f2bf(e[7]*inv));
}

extern "C" void kernel_launch(void* const* d_in, const int* in_sizes, int n_in,
                              void* d_out, int out_size, void* d_ws, size_t ws_size,
                              hipStream_t stream) {
  (void)in_sizes; (void)n_in; (void)out_size;

  const float* Qin  = (const float*)d_in[0];
  const float* Kin  = (const float*)d_in[1];
  const float* Vin  = (const float*)d_in[2];
  const int*   Kmask = (const int*)d_in[3];
  const float* Wq = (const float*)d_in[4];
  const float* bq = (const float*)d_in[5];
  const float* Wk = (const float*)d_in[6];
  const float* bk = (const float*)d_in[7];
  const float* Wv = (const float*)d_in[8];
  const float* bv = (const float*)d_in[9];

  char* ws = (char*)d_ws;
  const size_t MB = 1024UL * 1024UL;
  const dim3 blk(256);
  const dim3 gblk(512);
  const float rs = 0.03125f;  // 1/sqrt(1024)

  if (ws_size >= 226 * MB) {
    // [0,32) qb  [32,64) kb  [64,96) vT  [96,160) P (head hosts Wb in proj
    // phase)  [160,224) S fp16 all 8 batches
    u16*  qb = (u16*)(ws);
    u16*  vT = (u16*)(ws + 64 * MB);
    u16*  Wb = (u16*)(ws + 96 * MB);     // 6 MB, dead before softmax writes P
    u16*  P  = (u16*)(ws + 96 * MB);
    u16*  S  = (u16*)(ws + 160 * MB);

    cvtw3<<<dim3(1024, 1, 3), blk, 0, stream>>>(Wq, Wk, Wv, Wb);
    proj3_gemm<<<dim3(4, 64, 3), gblk, 0, stream>>>(Qin, Kin, Vin, Wb,
        bq, bk, bv, qb, vT);

    qk_gemm<<<dim3(8, 8, 8), gblk, 0, stream>>>(qb, qb + 16777216L, S,
        2048, 2048, 1024, 2048L * 1024, 2048L * 1024, 2048L * 2048, rs);
    softmax_rows_h<<<dim3(16384), blk, 0, stream>>>(S, Kmask, P);

    pv_gemm<<<dim3(4, 8, 8), gblk, 0, stream>>>(P, vT, d_out,
        2048, 1024, 2048, 2048L * 2048, 1024L * 2048, 2048L * 1024, 1.f);
  } else if (ws_size >= 194 * MB) {
    // Wb overlaps P head; S fp16 4 batches at 160-192
    u16*  qb = (u16*)(ws);
    u16*  vT = (u16*)(ws + 64 * MB);
    u16*  Wb = (u16*)(ws + 96 * MB);
    u16*  P  = (u16*)(ws + 96 * MB);
    u16*  S  = (u16*)(ws + 160 * MB);

    cvtw3<<<dim3(1024, 1, 3), blk, 0, stream>>>(Wq, Wk, Wv, Wb);
    proj3_gemm<<<dim3(4, 64, 3), gblk, 0, stream>>>(Qin, Kin, Vin, Wb,
        bq, bk, bv, qb, vT);

    for (int h = 0; h < 2; h++) {
      const u16* qbH = qb + (long)(4 * h) * 2048 * 1024;
      const u16* kbH = qb + 16777216L + (long)(4 * h) * 2048 * 1024;
      qk_gemm<<<dim3(8, 8, 4), gblk, 0, stream>>>(qbH, kbH, S,
          2048, 2048, 1024, 2048L * 1024, 2048L * 1024, 2048L * 2048, rs);
      softmax_rows_h<<<dim3(8192), blk, 0, stream>>>(
          S, Kmask + (long)(4 * h) * 2048, P + (long)(4 * h) * 2048 * 2048);
    }

    pv_gemm<<<dim3(4, 8, 8), gblk, 0, stream>>>(P, vT, d_out,
        2048, 1024, 2048, 2048L * 2048, 1024L * 2048, 2048L * 1024, 1.f);
  } else {
    // 120 MB fallback: per-batch S/P streaming
    u16*  qb = (u16*)(ws);
    u16*  vT = (u16*)(ws + 64 * MB);
    u16*  Wb = (u16*)(ws + 96 * MB);         // 6 MB
    u16*  S  = (u16*)(ws + 104 * MB);        // 8 MB fp16
    u16*  P  = (u16*)(ws + 112 * MB);        // 8 MB bf16

    cvtw3<<<dim3(1024, 1, 3), blk, 0, stream>>>(Wq, Wk, Wv, Wb);
    proj3_gemm<<<dim3(4, 64, 3), gblk, 0, stream>>>(Qin, Kin, Vin, Wb,
        bq, bk, bv, qb, vT);

    for (int b = 0; b < 8; b++) {
      const u16* qbB = qb + (long)b * 2048 * 1024;
      const u16* kbB = qb + 16777216L + (long)b * 2048 * 1024;
      const u16* vTB = vT + (long)b * 1024 * 2048;
      float* outB = (float*)d_out + (long)b * 2048 * 1024;

      qk_gemm<<<dim3(8, 8, 1), gblk, 0, stream>>>(qbB, kbB, S,
          2048, 2048, 1024, 0, 0, 0, rs);
      softmax_rows_h<<<dim3(2048), blk, 0, stream>>>(S, Kmask + (long)b * 2048, P);
      pv_gemm<<<dim3(4, 8, 1), gblk, 0, stream>>>(P, vTB, outB,
          2048, 1024, 2048, 0, 0, 0, 1.f);
    }
  }
}

// Round 10
// 336.740 us; speedup vs baseline: 1.2738x; 1.2738x over previous
//
#include <hip/hip_runtime.h>

// ---------------------------------------------------------------------------
// ScaleDotProductAttention: q=Q@Wq^T+bq; k=K@Wk^T+bk; v=V@Wv^T+bv
// S = q@k^T/32 (mask==1 -> -inf), P=softmax(S), out = P@v
// B=8, L1=L2=2048, D=E=1024. bf16 MFMA 16x16x32, fp32 accum.
// Round 10: revert round-9 convert fusion (2nd failure — reg-staging is
// latency-bound at 1 block/CU; abandoned). Round-8 schedule restored.
// NEW: LDS-transpose epilogues — counters showed 2.2x write amplification
// (qk WRITE 142MB vs 64 ideal) from scalar 2B/4B fragment stores; now waves
// transpose through their 16KB LDS region and store 16B/lane full lines.
// vT output packs 4 consecutive rows into one 8B store.
// ---------------------------------------------------------------------------

using u16 = unsigned short;
using frag_ab = __attribute__((ext_vector_type(8))) short;   // 8 bf16 (4 VGPRs)
using frag_cd = __attribute__((ext_vector_type(4))) float;   // 4 fp32

#define BAR() asm volatile("s_barrier" ::: "memory")
#define WAITV(n) asm volatile("s_waitcnt vmcnt(" #n ")" ::: "memory")
#define WAITLGKM0() do { asm volatile("s_waitcnt lgkmcnt(0)" ::: "memory"); \
                         __builtin_amdgcn_sched_barrier(0); } while (0)
#define L(d, ab, h) (lds + (((d) * 4) + ((ab) * 2) + (h)) * 8192)

__device__ __forceinline__ u16 f2bf(float f) {
  union { float f; unsigned u; } c; c.f = f;
  unsigned u = c.u;
  return (u16)((u + 0x7FFFu + ((u >> 16) & 1u)) >> 16);   // RNE
}
__device__ __forceinline__ u16 f2h(float f) {
  union { _Float16 h; u16 u; } c; c.h = (_Float16)f; return c.u;
}
__device__ __forceinline__ float h2f(u16 u) {
  union { u16 u; _Float16 h; } c; c.u = u; return (float)c.h;
}

__device__ __forceinline__ void async_ld16(const void* g, void* l) {
  __builtin_amdgcn_global_load_lds(
      (const __attribute__((address_space(1))) unsigned*)g,
      (__attribute__((address_space(3))) unsigned*)l, 16, 0, 0);
}

// weights fp32 -> bf16, one 3-way dispatch
__global__ void cvtw3(const float* __restrict__ a, const float* __restrict__ b,
                      const float* __restrict__ c, u16* __restrict__ out) {
  const float* in = blockIdx.z == 0 ? a : (blockIdx.z == 1 ? b : c);
  u16* o = out + (long)blockIdx.z * 1048576L;
  long i = ((long)blockIdx.x * 256 + threadIdx.x) * 4;
  float4 v = *reinterpret_cast<const float4*>(in + i);
  *reinterpret_cast<ushort4*>(o + i) =
      make_ushort4(f2bf(v.x), f2bf(v.y), f2bf(v.z), f2bf(v.w));
}

// Q,K,V inputs fp32 -> bf16 in one dispatch; dest stride 16M elements
__global__ void cvt3_f32_bf16(const float* __restrict__ q, const float* __restrict__ k,
                              const float* __restrict__ v, u16* __restrict__ out) {
  const float* in = blockIdx.z == 0 ? q : (blockIdx.z == 1 ? k : v);
  u16* o = out + (long)blockIdx.z * 16777216L;
  long i = ((long)blockIdx.x * 256 + threadIdx.x) * 4;
  float4 x = *reinterpret_cast<const float4*>(in + i);
  *reinterpret_cast<ushort4*>(o + i) =
      make_ushort4(f2bf(x.x), f2bf(x.y), f2bf(x.z), f2bf(x.w));
}

// Stage one 128x64 bf16 half-tile via global_load_lds (linear dest,
// 3-bit XOR swizzle pre-applied to the GLOBAL source 16B-slot).
__device__ __forceinline__ void stage_half(const u16* __restrict__ g_rowbase,
                                           long Kstr, u16* l_half,
                                           int wave, int lane) {
  const int t = wave * 64 + lane;
  #pragma unroll
  for (int i = 0; i < 2; i++) {
    const int row = i * 64 + (t >> 3);
    const int cb  = (t & 7) * 16;
    const int cbs = cb ^ ((row & 7) << 4);
    async_ld16(g_rowbase + (long)row * Kstr + (cbs >> 1),
               l_half + i * 4096 + wave * 512);
  }
}

// swizzled fragment read: 8 bf16 at (row r, k..k+7) of a [128][64] half
__device__ __forceinline__ frag_ab ld_frag(const u16* half_base, int r, int k) {
  const int idx = r * 64 + (k ^ ((r & 7) << 3));
  return *reinterpret_cast<const frag_ab*>(half_base + idx);
}

// C = scale * (A @ Bt^T) + bias.  A:[M][K] bf16, Bt:[N][K] bf16 row-major.
// OUT_MODE: 0 fp32 C[M][N] (2-pass LDS-transpose epilogue);
//           1 bf16 C[M][N] (LDS-transpose); 3 fp16 C[M][N] (LDS-transpose);
//           2 bf16 vT[b][n][l2] (b=row>>11; packed ushort4 stores).
// 256x256 tile, BK=64, 8 waves (2M x 4N), 128KB LDS dbuf, ds_reads 12/4/4/4,
// A staged 4 phases ahead, B 5-7 phases ahead, one vmcnt(4) per K-tile.
template<int OUT_MODE>
__device__ __forceinline__ void
gemm256_body(const u16* __restrict__ A, const u16* __restrict__ Bt,
             void* __restrict__ Cout, const float* __restrict__ bias,
             int M, int N, int K, long sA, long sB, long sC, float scale,
             u16* lds)
{
  // bijective XCD swizzle over the FULL grid (z folded in)
  const int gx = gridDim.x, gy = gridDim.y, gz = gridDim.z;
  const int nwg = gx * gy * gz;
  const int lin = ((int)blockIdx.z * gy + blockIdx.y) * gx + blockIdx.x;
  const int q8 = nwg >> 3, r8 = nwg & 7;
  const int xcd = lin & 7, idx8 = lin >> 3;
  const int swz = (xcd < r8 ? xcd * (q8 + 1) : r8 * (q8 + 1) + (xcd - r8) * q8) + idx8;
  const int z = swz / (gx * gy);
  const int rem = swz % (gx * gy);
  const int m0 = (rem / gx) * 256;
  const int n0 = (rem % gx) * 256;

  const u16* Ab = A + (long)z * sA;
  const u16* Bb = Bt + (long)z * sB;

  const int tid = threadIdx.x;
  const int wave = tid >> 6, lane = tid & 63;
  const int wm = wave >> 2, wn = wave & 3;
  const int ln15 = lane & 15, kof = (lane >> 4) * 8;
  const int rB0 = (wn & 1) * 64;
  const int NT = K >> 6;

  frag_cd acc[8][4];
  #pragma unroll
  for (int i = 0; i < 8; i++)
    #pragma unroll
    for (int j = 0; j < 4; j++)
      acc[i][j] = (frag_cd){0.f, 0.f, 0.f, 0.f};

  // prologue: A(0), B(0) -> dbuf0; B(1) -> dbuf1; drain A0/B0
  stage_half(Ab + (long)(m0 +   0) * K, K, L(0, 0, 0), wave, lane);
  stage_half(Ab + (long)(m0 + 128) * K, K, L(0, 0, 1), wave, lane);
  stage_half(Bb + (long)(n0 +   0) * K, K, L(0, 1, 0), wave, lane);
  stage_half(Bb + (long)(n0 + 128) * K, K, L(0, 1, 1), wave, lane);
  {
    const int t1 = (1 < NT) ? 1 : 0;
    stage_half(Bb + (long)(n0 +   0) * K + t1 * 64, K, L(1, 1, 0), wave, lane);
    stage_half(Bb + (long)(n0 + 128) * K + t1 * 64, K, L(1, 1, 1), wave, lane);
  }
  WAITV(4);
  BAR();

  for (int t = 0; t < NT; ++t) {
    const int d = t & 1;
    const u16* Al = L(d, 0, wm);
    const u16* Bl = L(d, 1, wn >> 1);
    const int tA = (t + 1 < NT) ? t + 1 : NT - 1;
    const int tB = (t + 2 < NT) ? t + 2 : NT - 1;

    frag_ab bf[4][2], af[2][2];

    // q0: 12 reads; stage A(t+1) both halves; mfma am0-1
    #pragma unroll
    for (int bn = 0; bn < 4; ++bn)
      #pragma unroll
      for (int kk = 0; kk < 2; ++kk)
        bf[bn][kk] = ld_frag(Bl, rB0 + bn * 16 + ln15, kk * 32 + kof);
    #pragma unroll
    for (int am = 0; am < 2; ++am)
      #pragma unroll
      for (int kk = 0; kk < 2; ++kk)
        af[am][kk] = ld_frag(Al, am * 16 + ln15, kk * 32 + kof);
    stage_half(Ab + (long)(m0 +   0) * K + tA * 64, K, L(d ^ 1, 0, 0), wave, lane);
    stage_half(Ab + (long)(m0 + 128) * K + tA * 64, K, L(d ^ 1, 0, 1), wave, lane);
    BAR();
    __builtin_amdgcn_s_setprio(1);
    #pragma unroll
    for (int am = 0; am < 2; ++am)
      #pragma unroll
      for (int bn = 0; bn < 4; ++bn)
        #pragma unroll
        for (int kk = 0; kk < 2; ++kk)
          acc[am][bn] = __builtin_amdgcn_mfma_f32_16x16x32_bf16(af[am][kk], bf[bn][kk], acc[am][bn], 0, 0, 0);
    __builtin_amdgcn_s_setprio(0);
    BAR();

    // q1: 4 reads; stage Bh0(t+2); mfma am2-3
    #pragma unroll
    for (int am = 0; am < 2; ++am)
      #pragma unroll
      for (int kk = 0; kk < 2; ++kk)
        af[am][kk] = ld_frag(Al, (2 + am) * 16 + ln15, kk * 32 + kof);
    stage_half(Bb + (long)(n0 + 0) * K + tB * 64, K, L(d, 1, 0), wave, lane);
    BAR();
    __builtin_amdgcn_s_setprio(1);
    #pragma unroll
    for (int am = 0; am < 2; ++am)
      #pragma unroll
      for (int bn = 0; bn < 4; ++bn)
        #pragma unroll
        for (int kk = 0; kk < 2; ++kk)
          acc[2 + am][bn] = __builtin_amdgcn_mfma_f32_16x16x32_bf16(af[am][kk], bf[bn][kk], acc[2 + am][bn], 0, 0, 0);
    __builtin_amdgcn_s_setprio(0);
    BAR();

    // q2: 4 reads; stage Bh1(t+2); mfma am4-5
    #pragma unroll
    for (int am = 0; am < 2; ++am)
      #pragma unroll
      for (int kk = 0; kk < 2; ++kk)
        af[am][kk] = ld_frag(Al, (4 + am) * 16 + ln15, kk * 32 + kof);
    stage_half(Bb + (long)(n0 + 128) * K + tB * 64, K, L(d, 1, 1), wave, lane);
    BAR();
    __builtin_amdgcn_s_setprio(1);
    #pragma unroll
    for (int am = 0; am < 2; ++am)
      #pragma unroll
      for (int bn = 0; bn < 4; ++bn)
        #pragma unroll
        for (int kk = 0; kk < 2; ++kk)
          acc[4 + am][bn] = __builtin_amdgcn_mfma_f32_16x16x32_bf16(af[am][kk], bf[bn][kk], acc[4 + am][bn], 0, 0, 0);
    __builtin_amdgcn_s_setprio(0);
    BAR();

    // q3: 4 reads; mfma am6-7; per-tile vmcnt(4)
    #pragma unroll
    for (int am = 0; am < 2; ++am)
      #pragma unroll
      for (int kk = 0; kk < 2; ++kk)
        af[am][kk] = ld_frag(Al, (6 + am) * 16 + ln15, kk * 32 + kof);
    BAR();
    __builtin_amdgcn_s_setprio(1);
    #pragma unroll
    for (int am = 0; am < 2; ++am)
      #pragma unroll
      for (int bn = 0; bn < 4; ++bn)
        #pragma unroll
        for (int kk = 0; kk < 2; ++kk)
          acc[6 + am][bn] = __builtin_amdgcn_mfma_f32_16x16x32_bf16(af[am][kk], bf[bn][kk], acc[6 + am][bn], 0, 0, 0);
    __builtin_amdgcn_s_setprio(0);
    WAITV(4);
    BAR();
  }

  WAITV(0);
  BAR();   // all staging + all LDS reads done; LDS is now free for transpose

  const int cl = lane & 15;
  const int rb = (lane >> 4) * 4;

  if (OUT_MODE == 1 || OUT_MODE == 3) {
    // ---- 2-byte row-major output via per-wave LDS transpose ----
    // wave-local region: [128 rows][8 slots of 8 u16], slot = cb ^ ((row>>2)&7)
    u16* Wt = lds + wave * 8192;
    #pragma unroll
    for (int am = 0; am < 8; ++am)
      #pragma unroll
      for (int bn = 0; bn < 4; ++bn) {
        const int col = bn * 16 + cl;
        const float badd = bias ? bias[n0 + wn * 64 + col] : 0.f;
        #pragma unroll
        for (int r = 0; r < 4; ++r) {
          const int row = am * 16 + rb + r;
          const int slot = (col >> 3) ^ ((row >> 2) & 7);
          const float val = acc[am][bn][r] * scale + badd;
          Wt[row * 64 + slot * 8 + (col & 7)] = (OUT_MODE == 1) ? f2bf(val) : f2h(val);
        }
      }
    WAITLGKM0();   // wave-local: writes visible to own reads, no barrier
    u16* Cb = (u16*)Cout + (long)z * sC;
    #pragma unroll
    for (int i = 0; i < 16; ++i) {
      const int row = (lane >> 3) + i * 8;
      const int c = lane & 7;
      const int slot = c ^ ((row >> 2) & 7);
      frag_ab v = *reinterpret_cast<const frag_ab*>(Wt + row * 64 + slot * 8);
      const long grow = m0 + wm * 128 + row;
      const int gcol = n0 + wn * 64 + c * 8;
      *reinterpret_cast<frag_ab*>(Cb + grow * N + gcol) = v;
    }
  } else if (OUT_MODE == 0) {
    // ---- fp32 row-major output, 2 passes of 32 cols through LDS ----
    float* Wt = (float*)(void*)lds + wave * 4096;   // 16KB per wave
    float* Cb = (float*)Cout + (long)z * sC;
    #pragma unroll
    for (int p = 0; p < 2; ++p) {
      #pragma unroll
      for (int am = 0; am < 8; ++am)
        #pragma unroll
        for (int bn = 0; bn < 2; ++bn) {
          const int col = bn * 16 + cl;          // 0..31
          #pragma unroll
          for (int r = 0; r < 4; ++r) {
            const int row = am * 16 + rb + r;
            const int slot = (col >> 2) ^ ((row >> 2) & 7);
            Wt[row * 32 + slot * 4 + (col & 3)] = acc[am][2 * p + bn][r] * scale;
          }
        }
      WAITLGKM0();
      #pragma unroll
      for (int i = 0; i < 16; ++i) {
        const int row = (lane >> 3) + i * 8;
        const int c = lane & 7;
        const int slot = c ^ ((row >> 2) & 7);
        float4 v = *reinterpret_cast<const float4*>(Wt + row * 32 + slot * 4);
        const long grow = m0 + wm * 128 + row;
        const int gcol = n0 + wn * 64 + p * 32 + c * 4;
        *reinterpret_cast<float4*>(Cb + grow * N + gcol) = v;
      }
      if (p == 0) WAITLGKM0();   // reads done before pass-2 overwrites
    }
  } else {
    // ---- OUT_MODE 2: vT[b][n][l2]; 4 consecutive rows are contiguous ----
    #pragma unroll
    for (int bn = 0; bn < 4; ++bn) {
      const int gcol = n0 + wn * 64 + bn * 16 + cl;
      const float badd = bias ? bias[gcol] : 0.f;
      #pragma unroll
      for (int am = 0; am < 8; ++am) {
        const int grow0 = m0 + wm * 128 + am * 16 + rb;
        ushort4 pk;
        pk.x = f2bf(acc[am][bn][0] * scale + badd);
        pk.y = f2bf(acc[am][bn][1] * scale + badd);
        pk.z = f2bf(acc[am][bn][2] * scale + badd);
        pk.w = f2bf(acc[am][bn][3] * scale + badd);
        const int bb = grow0 >> 11, l2 = grow0 & 2047;
        *reinterpret_cast<ushort4*>((u16*)Cout + ((long)bb * N + gcol) * 2048L + l2) = pk;
      }
    }
  }
}

__global__ void __launch_bounds__(512, 2)
proj_gemm(const u16* A, const u16* Bt, void* C, const float* bias,
          int M, int N, int K, long sA, long sB, long sC, float scale) {
  __shared__ u16 lds[8 * 8192];
  gemm256_body<1>(A, Bt, C, bias, M, N, K, sA, sB, sC, scale, lds);
}
__global__ void __launch_bounds__(512, 2)
projv_gemm(const u16* A, const u16* Bt, void* C, const float* bias,
           int M, int N, int K, long sA, long sB, long sC, float scale) {
  __shared__ u16 lds[8 * 8192];
  gemm256_body<2>(A, Bt, C, bias, M, N, K, sA, sB, sC, scale, lds);
}
__global__ void __launch_bounds__(512, 2)
qk_gemm(const u16* A, const u16* Bt, void* C, const float* bias,
        int M, int N, int K, long sA, long sB, long sC, float scale) {
  __shared__ u16 lds[8 * 8192];
  gemm256_body<3>(A, Bt, C, bias, M, N, K, sA, sB, sC, scale, lds);
}
__global__ void __launch_bounds__(512, 2)
pv_gemm(const u16* A, const u16* Bt, void* C, const float* bias,
        int M, int N, int K, long sA, long sB, long sC, float scale) {
  __shared__ u16 lds[8 * 8192];
  gemm256_body<0>(A, Bt, C, bias, M, N, K, sA, sB, sC, scale, lds);
}

// softmax over fp16 S slab: blockIdx.x = row; mask batch = row>>11
__global__ void softmax_rows_h(const u16* __restrict__ S, const int* __restrict__ Km,
                               u16* __restrict__ P)
{
  const long row = blockIdx.x;
  const int b = (int)(row >> 11);
  const u16* s = S + row * 2048;
  const int* mask = Km + (long)b * 2048;
  u16* p = P + row * 2048;

  const int t = threadIdx.x;
  const int base = t * 8;

  ushort4 r0 = *reinterpret_cast<const ushort4*>(s + base);
  ushort4 r1 = *reinterpret_cast<const ushort4*>(s + base + 4);
  int4 mA = *reinterpret_cast<const int4*>(mask + base);
  int4 mB = *reinterpret_cast<const int4*>(mask + base + 4);

  float vals[8] = {h2f(r0.x), h2f(r0.y), h2f(r0.z), h2f(r0.w),
                   h2f(r1.x), h2f(r1.y), h2f(r1.z), h2f(r1.w)};
  const int mk[8] = {mA.x, mA.y, mA.z, mA.w, mB.x, mB.y, mB.z, mB.w};

  float mx = -3.0e38f;
  #pragma unroll
  for (int i = 0; i < 8; i++) if (!mk[i]) mx = fmaxf(mx, vals[i]);
  #pragma unroll
  for (int off = 32; off > 0; off >>= 1) mx = fmaxf(mx, __shfl_xor(mx, off));

  __shared__ float redm[4], reds[4];
  const int wave = t >> 6, lane = t & 63;
  if (lane == 0) redm[wave] = mx;
  __syncthreads();
  mx = fmaxf(fmaxf(redm[0], redm[1]), fmaxf(redm[2], redm[3]));

  float e[8]; float sum = 0.f;
  #pragma unroll
  for (int i = 0; i < 8; i++) { e[i] = mk[i] ? 0.f : __expf(vals[i] - mx); sum += e[i]; }
  #pragma unroll
  for (int off = 32; off > 0; off >>= 1) sum += __shfl_xor(sum, off);
  if (lane == 0) reds[wave] = sum;
  __syncthreads();
  sum = reds[0] + reds[1] + reds[2] + reds[3];
  const float inv = 1.f / sum;

  *reinterpret_cast<ushort4*>(p + base) =
      make_ushort4(f2bf(e[0]*inv), f2bf(e[1]*inv), f2bf(e[2]*inv), f2bf(e[3]*inv));
  *reinterpret_cast<ushort4*>(p + base + 4) =
      make_ushort4(f2bf(e[4]*inv), f2bf(e[5]*inv), f2bf(e[6]*inv), f2bf(e[7]*inv));
}

extern "C" void kernel_launch(void* const* d_in, const int* in_sizes, int n_in,
                              void* d_out, int out_size, void* d_ws, size_t ws_size,
                              hipStream_t stream) {
  (void)in_sizes; (void)n_in; (void)out_size;

  const float* Qin  = (const float*)d_in[0];
  const float* Kin  = (const float*)d_in[1];
  const float* Vin  = (const float*)d_in[2];
  const int*   Kmask = (const int*)d_in[3];
  const float* Wq = (const float*)d_in[4];
  const float* bq = (const float*)d_in[5];
  const float* Wk = (const float*)d_in[6];
  const float* bk = (const float*)d_in[7];
  const float* Wv = (const float*)d_in[8];
  const float* bv = (const float*)d_in[9];

  char* ws = (char*)d_ws;
  const size_t MB = 1024UL * 1024UL;
  const dim3 blk(256);
  const dim3 gblk(512);
  const float rs = 0.03125f;  // 1/sqrt(1024)

  if (ws_size >= 226 * MB) {
    // [0,32) qb  [32,64) kb  [64,96) vT
    // [96,160)  P bf16 / {Xq 96-128, Xk 128-160} during projections
    // [160,224) S fp16 all 8 batches / Xv 160-192 during projections
    // [224,230) Wb (3x 2MB)
    u16*  qb = (u16*)(ws);
    u16*  kb = (u16*)(ws + 32 * MB);
    u16*  vT = (u16*)(ws + 64 * MB);
    u16*  P  = (u16*)(ws + 96 * MB);
    u16*  Xq = (u16*)(ws + 96 * MB);     // 3x 16M-elem slabs at 96/128/160
    u16*  S  = (u16*)(ws + 160 * MB);
    u16*  Wb = (u16*)(ws + 224 * MB);

    cvt3_f32_bf16<<<dim3(16384, 1, 3), blk, 0, stream>>>(Qin, Kin, Vin, Xq);
    cvtw3<<<dim3(1024, 1, 3), blk, 0, stream>>>(Wq, Wk, Wv, Wb);

    proj_gemm<<<dim3(4, 64, 1), gblk, 0, stream>>>(Xq, Wb, qb, bq,
        16384, 1024, 1024, 0, 0, 0, 1.f);
    proj_gemm<<<dim3(4, 64, 1), gblk, 0, stream>>>(Xq + 16777216L, Wb + 1048576L, kb, bk,
        16384, 1024, 1024, 0, 0, 0, 1.f);
    projv_gemm<<<dim3(4, 64, 1), gblk, 0, stream>>>(Xq + 2L * 16777216L, Wb + 2L * 1048576L, vT, bv,
        16384, 1024, 1024, 0, 0, 0, 1.f);

    qk_gemm<<<dim3(8, 8, 8), gblk, 0, stream>>>(qb, kb, S, nullptr,
        2048, 2048, 1024, 2048L * 1024, 2048L * 1024, 2048L * 2048, rs);
    softmax_rows_h<<<dim3(16384), blk, 0, stream>>>(S, Kmask, P);

    pv_gemm<<<dim3(4, 8, 8), gblk, 0, stream>>>(P, vT, d_out, nullptr,
        2048, 1024, 2048, 2048L * 2048, 1024L * 2048, 2048L * 1024, 1.f);
  } else if (ws_size >= 194 * MB) {
    // S fp16 4 batches at 160-192; two qk/softmax passes
    u16*  qb = (u16*)(ws);
    u16*  kb = (u16*)(ws + 32 * MB);
    u16*  vT = (u16*)(ws + 64 * MB);
    u16*  P  = (u16*)(ws + 96 * MB);
    u16*  Xq = (u16*)(ws + 96 * MB);
    u16*  S  = (u16*)(ws + 160 * MB);
    u16*  Wb = (u16*)(ws + 186 * MB);

    cvt3_f32_bf16<<<dim3(16384, 1, 3), blk, 0, stream>>>(Qin, Kin, Vin, Xq);
    cvtw3<<<dim3(1024, 1, 3), blk, 0, stream>>>(Wq, Wk, Wv, Wb);

    proj_gemm<<<dim3(4, 64, 1), gblk, 0, stream>>>(Xq, Wb, qb, bq,
        16384, 1024, 1024, 0, 0, 0, 1.f);
    proj_gemm<<<dim3(4, 64, 1), gblk, 0, stream>>>(Xq + 16777216L, Wb + 1048576L, kb, bk,
        16384, 1024, 1024, 0, 0, 0, 1.f);
    projv_gemm<<<dim3(4, 64, 1), gblk, 0, stream>>>(Xq + 2L * 16777216L, Wb + 2L * 1048576L, vT, bv,
        16384, 1024, 1024, 0, 0, 0, 1.f);

    for (int h = 0; h < 2; h++) {
      const u16* qbH = qb + (long)(4 * h) * 2048 * 1024;
      const u16* kbH = kb + (long)(4 * h) * 2048 * 1024;
      qk_gemm<<<dim3(8, 8, 4), gblk, 0, stream>>>(qbH, kbH, S, nullptr,
          2048, 2048, 1024, 2048L * 1024, 2048L * 1024, 2048L * 2048, rs);
      softmax_rows_h<<<dim3(8192), blk, 0, stream>>>(
          S, Kmask + (long)(4 * h) * 2048, P + (long)(4 * h) * 2048 * 2048);
    }

    pv_gemm<<<dim3(4, 8, 8), gblk, 0, stream>>>(P, vT, d_out, nullptr,
        2048, 1024, 2048, 2048L * 2048, 1024L * 2048, 2048L * 1024, 1.f);
  } else {
    // 130 MB fallback: per-batch S/P streaming, separate converts
    u16*  qb = (u16*)(ws);
    u16*  kb = (u16*)(ws + 32 * MB);
    u16*  vT = (u16*)(ws + 64 * MB);
    u16*  Xb = (u16*)(ws + 96 * MB);
    u16*  S  = (u16*)(ws + 96 * MB);
    u16*  P  = (u16*)(ws + 104 * MB);
    u16*  Wb = (u16*)(ws + 128 * MB);
    const long NQKV = 8L * 2048 * 1024;
    const long NW = 1024L * 1024;

    cvtw3<<<dim3(1024, 1, 3), blk, 0, stream>>>(Wq, Wk, Wv, Wb);
    cvt3_f32_bf16<<<dim3(16384, 1, 1), blk, 0, stream>>>(Qin, Qin, Qin, Xb);
    proj_gemm<<<dim3(4, 64, 1), gblk, 0, stream>>>(Xb, Wb, qb, bq,
        16384, 1024, 1024, 0, 0, 0, 1.f);
    cvt3_f32_bf16<<<dim3(16384, 1, 1), blk, 0, stream>>>(Kin, Kin, Kin, Xb);
    proj_gemm<<<dim3(4, 64, 1), gblk, 0, stream>>>(Xb, Wb + 1048576L, kb, bk,
        16384, 1024, 1024, 0, 0, 0, 1.f);
    cvt3_f32_bf16<<<dim3(16384, 1, 1), blk, 0, stream>>>(Vin, Vin, Vin, Xb);
    projv_gemm<<<dim3(4, 64, 1), gblk, 0, stream>>>(Xb, Wb + 2L * 1048576L, vT, bv,
        16384, 1024, 1024, 0, 0, 0, 1.f);
    (void)NQKV; (void)NW;

    for (int b = 0; b < 8; b++) {
      const u16* qbB = qb + (long)b * 2048 * 1024;
      const u16* kbB = kb + (long)b * 2048 * 1024;
      const u16* vTB = vT + (long)b * 1024 * 2048;
      float* outB = (float*)d_out + (long)b * 2048 * 1024;

      qk_gemm<<<dim3(8, 8, 1), gblk, 0, stream>>>(qbB, kbB, S, nullptr,
          2048, 2048, 1024, 0, 0, 0, rs);
      softmax_rows_h<<<dim3(2048), blk, 0, stream>>>(S, Kmask + (long)b * 2048, P);
      pv_gemm<<<dim3(4, 8, 1), gblk, 0, stream>>>(P, vTB, outB, nullptr,
          2048, 1024, 2048, 0, 0, 0, 1.f);
    }
  }
}

// Round 11
// 329.699 us; speedup vs baseline: 1.3010x; 1.0214x over previous
//
#include <hip/hip_runtime.h>

// ---------------------------------------------------------------------------
// ScaleDotProductAttention: q=Q@Wq^T+bq; k=K@Wk^T+bk; v=V@Wv^T+bv
// S = q@k^T/32 (mask==1 -> -inf), P=softmax(S), out = P@v
// B=8, L1=L2=2048, D=E=1024. bf16 MFMA 16x16x32, fp32 accum.
// Round 11: m201-faithful fine staging interleave — ONE half-tile staged per
// phase (1-1-1-1, was 2-2-0-0), lgkmcnt(8) hint in the 12-read phase,
// in-flight ledger re-derived (vmcnt(4)/tile unchanged). Projections merged
// into one z=3 dispatch (launch merge only; convert fusion stays abandoned).
// Epilogues (round 10, verified): LDS-transpose for row-major, packed for vT.
// ---------------------------------------------------------------------------

using u16 = unsigned short;
using frag_ab = __attribute__((ext_vector_type(8))) short;   // 8 bf16 (4 VGPRs)
using frag_cd = __attribute__((ext_vector_type(4))) float;   // 4 fp32

#define BAR() asm volatile("s_barrier" ::: "memory")
#define WAITV(n) asm volatile("s_waitcnt vmcnt(" #n ")" ::: "memory")
#define WAITLGKM0() do { asm volatile("s_waitcnt lgkmcnt(0)" ::: "memory"); \
                         __builtin_amdgcn_sched_barrier(0); } while (0)
#define HINT_LGKM8() asm volatile("s_waitcnt lgkmcnt(8)" ::: "memory")
#define L(d, ab, h) (lds + (((d) * 4) + ((ab) * 2) + (h)) * 8192)

__device__ __forceinline__ u16 f2bf(float f) {
  union { float f; unsigned u; } c; c.f = f;
  unsigned u = c.u;
  return (u16)((u + 0x7FFFu + ((u >> 16) & 1u)) >> 16);   // RNE
}
__device__ __forceinline__ u16 f2h(float f) {
  union { _Float16 h; u16 u; } c; c.h = (_Float16)f; return c.u;
}
__device__ __forceinline__ float h2f(u16 u) {
  union { u16 u; _Float16 h; } c; c.u = u; return (float)c.h;
}

__device__ __forceinline__ void async_ld16(const void* g, void* l) {
  __builtin_amdgcn_global_load_lds(
      (const __attribute__((address_space(1))) unsigned*)g,
      (__attribute__((address_space(3))) unsigned*)l, 16, 0, 0);
}

// weights fp32 -> bf16, one 3-way dispatch
__global__ void cvtw3(const float* __restrict__ a, const float* __restrict__ b,
                      const float* __restrict__ c, u16* __restrict__ out) {
  const float* in = blockIdx.z == 0 ? a : (blockIdx.z == 1 ? b : c);
  u16* o = out + (long)blockIdx.z * 1048576L;
  long i = ((long)blockIdx.x * 256 + threadIdx.x) * 4;
  float4 v = *reinterpret_cast<const float4*>(in + i);
  *reinterpret_cast<ushort4*>(o + i) =
      make_ushort4(f2bf(v.x), f2bf(v.y), f2bf(v.z), f2bf(v.w));
}

// Q,K,V inputs fp32 -> bf16 in one dispatch; dest stride 16M elements
__global__ void cvt3_f32_bf16(const float* __restrict__ q, const float* __restrict__ k,
                              const float* __restrict__ v, u16* __restrict__ out) {
  const float* in = blockIdx.z == 0 ? q : (blockIdx.z == 1 ? k : v);
  u16* o = out + (long)blockIdx.z * 16777216L;
  long i = ((long)blockIdx.x * 256 + threadIdx.x) * 4;
  float4 x = *reinterpret_cast<const float4*>(in + i);
  *reinterpret_cast<ushort4*>(o + i) =
      make_ushort4(f2bf(x.x), f2bf(x.y), f2bf(x.z), f2bf(x.w));
}

// Stage one 128x64 bf16 half-tile via global_load_lds (linear dest,
// 3-bit XOR swizzle pre-applied to the GLOBAL source 16B-slot).
__device__ __forceinline__ void stage_half(const u16* __restrict__ g_rowbase,
                                           long Kstr, u16* l_half,
                                           int wave, int lane) {
  const int t = wave * 64 + lane;
  #pragma unroll
  for (int i = 0; i < 2; i++) {
    const int row = i * 64 + (t >> 3);
    const int cb  = (t & 7) * 16;
    const int cbs = cb ^ ((row & 7) << 4);
    async_ld16(g_rowbase + (long)row * Kstr + (cbs >> 1),
               l_half + i * 4096 + wave * 512);
  }
}

// swizzled fragment read: 8 bf16 at (row r, k..k+7) of a [128][64] half
__device__ __forceinline__ frag_ab ld_frag(const u16* half_base, int r, int k) {
  const int idx = r * 64 + (k ^ ((r & 7) << 3));
  return *reinterpret_cast<const frag_ab*>(half_base + idx);
}

// Bijective XCD swizzle over the FULL grid (z folded in)
struct SwzOut { int z, m0, n0; };
__device__ __forceinline__ SwzOut grid_swizzle() {
  const int gx = gridDim.x, gy = gridDim.y, gz = gridDim.z;
  const int nwg = gx * gy * gz;
  const int lin = ((int)blockIdx.z * gy + blockIdx.y) * gx + blockIdx.x;
  const int q8 = nwg >> 3, r8 = nwg & 7;
  const int xcd = lin & 7, idx8 = lin >> 3;
  const int swz = (xcd < r8 ? xcd * (q8 + 1) : r8 * (q8 + 1) + (xcd - r8) * q8) + idx8;
  SwzOut o;
  o.z = swz / (gx * gy);
  const int rem = swz % (gx * gy);
  o.m0 = (rem / gx) * 256;
  o.n0 = (rem % gx) * 256;
  return o;
}

// C = scale * (A @ Bt^T) + bias, one 256x256 tile at (m0, n0).
// out_mode: 0 fp32 row-major; 1 bf16 row-major; 3 fp16 row-major
//           (all via LDS-transpose, 16B/lane stores);
//           2 bf16 vT[b][gcol][l2] with b=grow>>11 (packed ushort4).
// Cb is already z-offset for modes 0/1/3; global vT base for mode 2.
// K-loop: BK=64, 8 waves (2M x 4N), 128KB LDS dbuf, ds_reads 12/4/4/4,
// staging 1 half-tile per phase (q0,q1: A(t+1); q2,q3: B(t+2)), vmcnt(4)/tile.
__device__ __forceinline__ void
gemm256_core(int out_mode, const u16* __restrict__ Ab, const u16* __restrict__ Bb,
             void* __restrict__ Cb, const float* __restrict__ bias,
             int N, int K, int m0, int n0, float scale, u16* lds)
{
  const int tid = threadIdx.x;
  const int wave = tid >> 6, lane = tid & 63;
  const int wm = wave >> 2, wn = wave & 3;
  const int ln15 = lane & 15, kof = (lane >> 4) * 8;
  const int rB0 = (wn & 1) * 64;
  const int NT = K >> 6;

  frag_cd acc[8][4];
  #pragma unroll
  for (int i = 0; i < 8; i++)
    #pragma unroll
    for (int j = 0; j < 4; j++)
      acc[i][j] = (frag_cd){0.f, 0.f, 0.f, 0.f};

  // prologue: A(0),B(0) -> dbuf0; B(1) -> dbuf1; drain A0/B0 (B1 in flight)
  stage_half(Ab + (long)(m0 +   0) * K, K, L(0, 0, 0), wave, lane);
  stage_half(Ab + (long)(m0 + 128) * K, K, L(0, 0, 1), wave, lane);
  stage_half(Bb + (long)(n0 +   0) * K, K, L(0, 1, 0), wave, lane);
  stage_half(Bb + (long)(n0 + 128) * K, K, L(0, 1, 1), wave, lane);
  {
    const int t1 = (1 < NT) ? 1 : 0;
    stage_half(Bb + (long)(n0 +   0) * K + t1 * 64, K, L(1, 1, 0), wave, lane);
    stage_half(Bb + (long)(n0 + 128) * K + t1 * 64, K, L(1, 1, 1), wave, lane);
  }
  WAITV(4);
  BAR();

  for (int t = 0; t < NT; ++t) {
    const int d = t & 1;
    const u16* Al = L(d, 0, wm);
    const u16* Bl = L(d, 1, wn >> 1);
    const int tA = (t + 1 < NT) ? t + 1 : NT - 1;
    const int tB = (t + 2 < NT) ? t + 2 : NT - 1;

    frag_ab bf[4][2], af[2][2];

    // q0: 12 ds_reads; stage A(t+1) h0; lgkm hint; mfma am0-1
    #pragma unroll
    for (int bn = 0; bn < 4; ++bn)
      #pragma unroll
      for (int kk = 0; kk < 2; ++kk)
        bf[bn][kk] = ld_frag(Bl, rB0 + bn * 16 + ln15, kk * 32 + kof);
    #pragma unroll
    for (int am = 0; am < 2; ++am)
      #pragma unroll
      for (int kk = 0; kk < 2; ++kk)
        af[am][kk] = ld_frag(Al, am * 16 + ln15, kk * 32 + kof);
    stage_half(Ab + (long)(m0 + 0) * K + tA * 64, K, L(d ^ 1, 0, 0), wave, lane);
    HINT_LGKM8();
    BAR();
    __builtin_amdgcn_s_setprio(1);
    #pragma unroll
    for (int am = 0; am < 2; ++am)
      #pragma unroll
      for (int bn = 0; bn < 4; ++bn)
        #pragma unroll
        for (int kk = 0; kk < 2; ++kk)
          acc[am][bn] = __builtin_amdgcn_mfma_f32_16x16x32_bf16(af[am][kk], bf[bn][kk], acc[am][bn], 0, 0, 0);
    __builtin_amdgcn_s_setprio(0);
    BAR();

    // q1: 4 ds_reads; stage A(t+1) h1; mfma am2-3
    #pragma unroll
    for (int am = 0; am < 2; ++am)
      #pragma unroll
      for (int kk = 0; kk < 2; ++kk)
        af[am][kk] = ld_frag(Al, (2 + am) * 16 + ln15, kk * 32 + kof);
    stage_half(Ab + (long)(m0 + 128) * K + tA * 64, K, L(d ^ 1, 0, 1), wave, lane);
    BAR();
    __builtin_amdgcn_s_setprio(1);
    #pragma unroll
    for (int am = 0; am < 2; ++am)
      #pragma unroll
      for (int bn = 0; bn < 4; ++bn)
        #pragma unroll
        for (int kk = 0; kk < 2; ++kk)
          acc[2 + am][bn] = __builtin_amdgcn_mfma_f32_16x16x32_bf16(af[am][kk], bf[bn][kk], acc[2 + am][bn], 0, 0, 0);
    __builtin_amdgcn_s_setprio(0);
    BAR();

    // q2: 4 ds_reads; stage B(t+2) h0; mfma am4-5
    #pragma unroll
    for (int am = 0; am < 2; ++am)
      #pragma unroll
      for (int kk = 0; kk < 2; ++kk)
        af[am][kk] = ld_frag(Al, (4 + am) * 16 + ln15, kk * 32 + kof);
    stage_half(Bb + (long)(n0 + 0) * K + tB * 64, K, L(d, 1, 0), wave, lane);
    BAR();
    __builtin_amdgcn_s_setprio(1);
    #pragma unroll
    for (int am = 0; am < 2; ++am)
      #pragma unroll
      for (int bn = 0; bn < 4; ++bn)
        #pragma unroll
        for (int kk = 0; kk < 2; ++kk)
          acc[4 + am][bn] = __builtin_amdgcn_mfma_f32_16x16x32_bf16(af[am][kk], bf[bn][kk], acc[4 + am][bn], 0, 0, 0);
    __builtin_amdgcn_s_setprio(0);
    BAR();

    // q3: 4 ds_reads; stage B(t+2) h1; mfma am6-7; vmcnt(4)
    #pragma unroll
    for (int am = 0; am < 2; ++am)
      #pragma unroll
      for (int kk = 0; kk < 2; ++kk)
        af[am][kk] = ld_frag(Al, (6 + am) * 16 + ln15, kk * 32 + kof);
    stage_half(Bb + (long)(n0 + 128) * K + tB * 64, K, L(d, 1, 1), wave, lane);
    BAR();
    __builtin_amdgcn_s_setprio(1);
    #pragma unroll
    for (int am = 0; am < 2; ++am)
      #pragma unroll
      for (int bn = 0; bn < 4; ++bn)
        #pragma unroll
        for (int kk = 0; kk < 2; ++kk)
          acc[6 + am][bn] = __builtin_amdgcn_mfma_f32_16x16x32_bf16(af[am][kk], bf[bn][kk], acc[6 + am][bn], 0, 0, 0);
    __builtin_amdgcn_s_setprio(0);
    WAITV(4);   // drains A(t+1)+B(t+1); B(t+2) (4 newest) stays in flight
    BAR();
  }

  WAITV(0);
  BAR();   // staging drained, all waves past K-loop: LDS free for transpose

  const int cl = lane & 15;
  const int rb = (lane >> 4) * 4;

  if (out_mode == 1 || out_mode == 3) {
    // 2-byte row-major output via per-wave LDS transpose
    u16* Wt = lds + wave * 8192;
    #pragma unroll
    for (int am = 0; am < 8; ++am)
      #pragma unroll
      for (int bn = 0; bn < 4; ++bn) {
        const int col = bn * 16 + cl;
        const float badd = bias ? bias[n0 + wn * 64 + col] : 0.f;
        #pragma unroll
        for (int r = 0; r < 4; ++r) {
          const int row = am * 16 + rb + r;
          const int slot = (col >> 3) ^ ((row >> 2) & 7);
          const float val = acc[am][bn][r] * scale + badd;
          Wt[row * 64 + slot * 8 + (col & 7)] = (out_mode == 1) ? f2bf(val) : f2h(val);
        }
      }
    WAITLGKM0();
    u16* Cp = (u16*)Cb;
    #pragma unroll
    for (int i = 0; i < 16; ++i) {
      const int row = (lane >> 3) + i * 8;
      const int c = lane & 7;
      const int slot = c ^ ((row >> 2) & 7);
      frag_ab v = *reinterpret_cast<const frag_ab*>(Wt + row * 64 + slot * 8);
      const long grow = m0 + wm * 128 + row;
      const int gcol = n0 + wn * 64 + c * 8;
      *reinterpret_cast<frag_ab*>(Cp + grow * N + gcol) = v;
    }
  } else if (out_mode == 0) {
    // fp32 row-major output, 2 passes of 32 cols through LDS
    float* Wt = (float*)(void*)lds + wave * 4096;
    float* Cp = (float*)Cb;
    #pragma unroll
    for (int p = 0; p < 2; ++p) {
      #pragma unroll
      for (int am = 0; am < 8; ++am)
        #pragma unroll
        for (int bn = 0; bn < 2; ++bn) {
          const int col = bn * 16 + cl;
          #pragma unroll
          for (int r = 0; r < 4; ++r) {
            const int row = am * 16 + rb + r;
            const int slot = (col >> 2) ^ ((row >> 2) & 7);
            Wt[row * 32 + slot * 4 + (col & 3)] = acc[am][2 * p + bn][r] * scale;
          }
        }
      WAITLGKM0();
      #pragma unroll
      for (int i = 0; i < 16; ++i) {
        const int row = (lane >> 3) + i * 8;
        const int c = lane & 7;
        const int slot = c ^ ((row >> 2) & 7);
        float4 v = *reinterpret_cast<const float4*>(Wt + row * 32 + slot * 4);
        const long grow = m0 + wm * 128 + row;
        const int gcol = n0 + wn * 64 + p * 32 + c * 4;
        *reinterpret_cast<float4*>(Cp + grow * N + gcol) = v;
      }
      if (p == 0) WAITLGKM0();
    }
  } else {
    // out_mode 2: vT[b][gcol][l2]; 4 consecutive rows contiguous -> ushort4
    #pragma unroll
    for (int bn = 0; bn < 4; ++bn) {
      const int gcol = n0 + wn * 64 + bn * 16 + cl;
      const float badd = bias ? bias[gcol] : 0.f;
      #pragma unroll
      for (int am = 0; am < 8; ++am) {
        const int grow0 = m0 + wm * 128 + am * 16 + rb;
        ushort4 pk;
        pk.x = f2bf(acc[am][bn][0] * scale + badd);
        pk.y = f2bf(acc[am][bn][1] * scale + badd);
        pk.z = f2bf(acc[am][bn][2] * scale + badd);
        pk.w = f2bf(acc[am][bn][3] * scale + badd);
        const int bb = grow0 >> 11, l2 = grow0 & 2047;
        *reinterpret_cast<ushort4*>((u16*)Cb + ((long)bb * N + gcol) * 2048L + l2) = pk;
      }
    }
  }
}

// All three projections in one z=3 dispatch: z selects input/weight/bias;
// z<2 -> bf16 row-major into qkb slab z; z==2 -> vT packed.
__global__ void __launch_bounds__(512, 2)
proj3_gemm(const u16* __restrict__ X, const u16* __restrict__ Wb,
           const float* __restrict__ bq, const float* __restrict__ bk,
           const float* __restrict__ bv, u16* __restrict__ qkb,
           u16* __restrict__ vT)
{
  __shared__ u16 lds[8 * 8192];
  SwzOut s = grid_swizzle();
  const u16* A = X + (long)s.z * 16777216L;
  const u16* W = Wb + (long)s.z * 1048576L;
  const float* bias = s.z == 0 ? bq : (s.z == 1 ? bk : bv);
  if (s.z < 2)
    gemm256_core(1, A, W, qkb + (long)s.z * 16777216L, bias,
                 1024, 1024, s.m0, s.n0, 1.f, lds);
  else
    gemm256_core(2, A, W, vT, bias, 1024, 1024, s.m0, s.n0, 1.f, lds);
}

// single projection with explicit mode (fallback path)
__global__ void __launch_bounds__(512, 2)
proj1_gemm(int mode, const u16* A, const u16* W, void* C, const float* bias) {
  __shared__ u16 lds[8 * 8192];
  SwzOut s = grid_swizzle();
  gemm256_core(mode, A, W, C, bias, 1024, 1024, s.m0, s.n0, 1.f, lds);
}

__global__ void __launch_bounds__(512, 2)
qk_gemm(const u16* A, const u16* Bt, void* C,
        int M, int N, int K, long sA, long sB, long sC, float scale) {
  __shared__ u16 lds[8 * 8192];
  SwzOut s = grid_swizzle();
  gemm256_core(3, A + (long)s.z * sA, Bt + (long)s.z * sB,
               (u16*)C + (long)s.z * sC, nullptr, N, K, s.m0, s.n0, scale, lds);
}
__global__ void __launch_bounds__(512, 2)
pv_gemm(const u16* A, const u16* Bt, void* C,
        int M, int N, int K, long sA, long sB, long sC, float scale) {
  __shared__ u16 lds[8 * 8192];
  SwzOut s = grid_swizzle();
  gemm256_core(0, A + (long)s.z * sA, Bt + (long)s.z * sB,
               (float*)C + (long)s.z * sC, nullptr, N, K, s.m0, s.n0, scale, lds);
}

// softmax over fp16 S slab: blockIdx.x = row; mask batch = row>>11
__global__ void softmax_rows_h(const u16* __restrict__ S, const int* __restrict__ Km,
                               u16* __restrict__ P)
{
  const long row = blockIdx.x;
  const int b = (int)(row >> 11);
  const u16* s = S + row * 2048;
  const int* mask = Km + (long)b * 2048;
  u16* p = P + row * 2048;

  const int t = threadIdx.x;
  const int base = t * 8;

  ushort4 r0 = *reinterpret_cast<const ushort4*>(s + base);
  ushort4 r1 = *reinterpret_cast<const ushort4*>(s + base + 4);
  int4 mA = *reinterpret_cast<const int4*>(mask + base);
  int4 mB = *reinterpret_cast<const int4*>(mask + base + 4);

  float vals[8] = {h2f(r0.x), h2f(r0.y), h2f(r0.z), h2f(r0.w),
                   h2f(r1.x), h2f(r1.y), h2f(r1.z), h2f(r1.w)};
  const int mk[8] = {mA.x, mA.y, mA.z, mA.w, mB.x, mB.y, mB.z, mB.w};

  float mx = -3.0e38f;
  #pragma unroll
  for (int i = 0; i < 8; i++) if (!mk[i]) mx = fmaxf(mx, vals[i]);
  #pragma unroll
  for (int off = 32; off > 0; off >>= 1) mx = fmaxf(mx, __shfl_xor(mx, off));

  __shared__ float redm[4], reds[4];
  const int wave = t >> 6, lane = t & 63;
  if (lane == 0) redm[wave] = mx;
  __syncthreads();
  mx = fmaxf(fmaxf(redm[0], redm[1]), fmaxf(redm[2], redm[3]));

  float e[8]; float sum = 0.f;
  #pragma unroll
  for (int i = 0; i < 8; i++) { e[i] = mk[i] ? 0.f : __expf(vals[i] - mx); sum += e[i]; }
  #pragma unroll
  for (int off = 32; off > 0; off >>= 1) sum += __shfl_xor(sum, off);
  if (lane == 0) reds[wave] = sum;
  __syncthreads();
  sum = reds[0] + reds[1] + reds[2] + reds[3];
  const float inv = 1.f / sum;

  *reinterpret_cast<ushort4*>(p + base) =
      make_ushort4(f2bf(e[0]*inv), f2bf(e[1]*inv), f2bf(e[2]*inv), f2bf(e[3]*inv));
  *reinterpret_cast<ushort4*>(p + base + 4) =
      make_ushort4(f2bf(e[4]*inv), f2bf(e[5]*inv), f2bf(e[6]*inv), f2bf(e[7]*inv));
}

extern "C" void kernel_launch(void* const* d_in, const int* in_sizes, int n_in,
                              void* d_out, int out_size, void* d_ws, size_t ws_size,
                              hipStream_t stream) {
  (void)in_sizes; (void)n_in; (void)out_size;

  const float* Qin  = (const float*)d_in[0];
  const float* Kin  = (const float*)d_in[1];
  const float* Vin  = (const float*)d_in[2];
  const int*   Kmask = (const int*)d_in[3];
  const float* Wq = (const float*)d_in[4];
  const float* bq = (const float*)d_in[5];
  const float* Wk = (const float*)d_in[6];
  const float* bk = (const float*)d_in[7];
  const float* Wv = (const float*)d_in[8];
  const float* bv = (const float*)d_in[9];

  char* ws = (char*)d_ws;
  const size_t MB = 1024UL * 1024UL;
  const dim3 blk(256);
  const dim3 gblk(512);
  const float rs = 0.03125f;  // 1/sqrt(1024)

  if (ws_size >= 226 * MB) {
    // [0,32) qb  [32,64) kb  [64,96) vT
    // [96,160)  P bf16 / {Xq 96-128, Xk 128-160} during projections
    // [160,224) S fp16 all 8 batches / Xv 160-192 during projections
    // [224,230) Wb (3x 2MB)
    u16*  qb = (u16*)(ws);
    u16*  vT = (u16*)(ws + 64 * MB);
    u16*  P  = (u16*)(ws + 96 * MB);
    u16*  Xq = (u16*)(ws + 96 * MB);     // 3x 16M-elem slabs at 96/128/160
    u16*  S  = (u16*)(ws + 160 * MB);
    u16*  Wb = (u16*)(ws + 224 * MB);

    cvt3_f32_bf16<<<dim3(16384, 1, 3), blk, 0, stream>>>(Qin, Kin, Vin, Xq);
    cvtw3<<<dim3(1024, 1, 3), blk, 0, stream>>>(Wq, Wk, Wv, Wb);

    proj3_gemm<<<dim3(4, 64, 3), gblk, 0, stream>>>(Xq, Wb, bq, bk, bv, qb, vT);

    qk_gemm<<<dim3(8, 8, 8), gblk, 0, stream>>>(qb, qb + 16777216L, S,
        2048, 2048, 1024, 2048L * 1024, 2048L * 1024, 2048L * 2048, rs);
    softmax_rows_h<<<dim3(16384), blk, 0, stream>>>(S, Kmask, P);

    pv_gemm<<<dim3(4, 8, 8), gblk, 0, stream>>>(P, vT, d_out,
        2048, 1024, 2048, 2048L * 2048, 1024L * 2048, 2048L * 1024, 1.f);
  } else if (ws_size >= 194 * MB) {
    // S fp16 4 batches at 160-192 (Wb at 186-192: dead before S written)
    u16*  qb = (u16*)(ws);
    u16*  vT = (u16*)(ws + 64 * MB);
    u16*  P  = (u16*)(ws + 96 * MB);
    u16*  Xq = (u16*)(ws + 96 * MB);
    u16*  S  = (u16*)(ws + 160 * MB);
    u16*  Wb = (u16*)(ws + 186 * MB);

    cvt3_f32_bf16<<<dim3(16384, 1, 3), blk, 0, stream>>>(Qin, Kin, Vin, Xq);
    cvtw3<<<dim3(1024, 1, 3), blk, 0, stream>>>(Wq, Wk, Wv, Wb);

    proj3_gemm<<<dim3(4, 64, 3), gblk, 0, stream>>>(Xq, Wb, bq, bk, bv, qb, vT);

    for (int h = 0; h < 2; h++) {
      const u16* qbH = qb + (long)(4 * h) * 2048 * 1024;
      const u16* kbH = qb + 16777216L + (long)(4 * h) * 2048 * 1024;
      qk_gemm<<<dim3(8, 8, 4), gblk, 0, stream>>>(qbH, kbH, S,
          2048, 2048, 1024, 2048L * 1024, 2048L * 1024, 2048L * 2048, rs);
      softmax_rows_h<<<dim3(8192), blk, 0, stream>>>(
          S, Kmask + (long)(4 * h) * 2048, P + (long)(4 * h) * 2048 * 2048);
    }

    pv_gemm<<<dim3(4, 8, 8), gblk, 0, stream>>>(P, vT, d_out,
        2048, 1024, 2048, 2048L * 2048, 1024L * 2048, 2048L * 1024, 1.f);
  } else {
    // 130 MB fallback: per-input converts, per-batch S/P streaming
    u16*  qb = (u16*)(ws);
    u16*  kb = (u16*)(ws + 32 * MB);
    u16*  vT = (u16*)(ws + 64 * MB);
    u16*  Xb = (u16*)(ws + 96 * MB);
    u16*  S  = (u16*)(ws + 96 * MB);
    u16*  P  = (u16*)(ws + 104 * MB);
    u16*  Wb = (u16*)(ws + 128 * MB);

    cvtw3<<<dim3(1024, 1, 3), blk, 0, stream>>>(Wq, Wk, Wv, Wb);
    cvt3_f32_bf16<<<dim3(16384, 1, 1), blk, 0, stream>>>(Qin, Qin, Qin, Xb);
    proj1_gemm<<<dim3(4, 64, 1), gblk, 0, stream>>>(1, Xb, Wb, qb, bq);
    cvt3_f32_bf16<<<dim3(16384, 1, 1), blk, 0, stream>>>(Kin, Kin, Kin, Xb);
    proj1_gemm<<<dim3(4, 64, 1), gblk, 0, stream>>>(1, Xb, Wb + 1048576L, kb, bk);
    cvt3_f32_bf16<<<dim3(16384, 1, 1), blk, 0, stream>>>(Vin, Vin, Vin, Xb);
    proj1_gemm<<<dim3(4, 64, 1), gblk, 0, stream>>>(2, Xb, Wb + 2L * 1048576L, vT, bv);

    for (int b = 0; b < 8; b++) {
      const u16* qbB = qb + (long)b * 2048 * 1024;
      const u16* kbB = kb + (long)b * 2048 * 1024;
      const u16* vTB = vT + (long)b * 1024 * 2048;
      float* outB = (float*)d_out + (long)b * 2048 * 1024;

      qk_gemm<<<dim3(8, 8, 1), gblk, 0, stream>>>(qbB, kbB, S,
          2048, 2048, 1024, 0, 0, 0, rs);
      softmax_rows_h<<<dim3(2048), blk, 0, stream>>>(S, Kmask + (long)b * 2048, P);
      pv_gemm<<<dim3(4, 8, 1), gblk, 0, stream>>>(P, vTB, outB,
          2048, 1024, 2048, 0, 0, 0, 1.f);
    }
  }
}